// Round 1
// baseline (260404.395 us; speedup 1.0000x reference)
//
#include <hip/hip_runtime.h>

#define S_LEN 8192
#define HDIM 1024
#define TTAG 48
#define START_TAG 46
#define END_TAG 47
#define CHUNK 1024
#define NCHUNK 8

// ---------------------------------------------------------------------------
// Transpose W_dense (48 x 2048) -> WdT (2048 x 48) for coalesced feats loads
// ---------------------------------------------------------------------------
__global__ __launch_bounds__(256) void wdt_kernel(const float* __restrict__ Wd,
                                                  float* __restrict__ WdT) {
    int idx = blockIdx.x * 256 + threadIdx.x;
    if (idx < TTAG * 2048) {
        int tag = idx >> 11;       // / 2048
        int k = idx & 2047;
        WdT[(size_t)k * TTAG + tag] = Wd[idx];
    }
}

// ---------------------------------------------------------------------------
// xi GEMM: xi[m][n] = sum_k x[m][k] * W_ih[n][k] + (b_ih[n] + b_hh[n])
// Writes into permuted ring layout: xi_ring[(dir*128+slice)][i_local][32]
// where n = gate*1024 + slice*8 + e, within-slice index = gate*8 + e.
// dir=0 slab: rows m in [chunk*1024, ...); dir=1 slab: rows for reversed x.
// ---------------------------------------------------------------------------
__global__ __launch_bounds__(256) void gemm_xi(
    const float* __restrict__ x,
    const float* __restrict__ Wf, const float* __restrict__ Wb,
    const float* __restrict__ bihf, const float* __restrict__ bhhf,
    const float* __restrict__ bihb, const float* __restrict__ bhhb,
    float* __restrict__ xi_ring, int chunk) {
    const int dir = blockIdx.z;
    const float* __restrict__ W = dir ? Wb : Wf;
    const float* __restrict__ bih = dir ? bihb : bihf;
    const float* __restrict__ bhh = dir ? bhhb : bhhf;

    const int mloc0 = blockIdx.y * 64;  // 0..960 within chunk slab
    const int m0 = (dir == 0 ? chunk * CHUNK : S_LEN - (chunk + 1) * CHUNK) + mloc0;
    const int n0 = blockIdx.x * 64;

    __shared__ float As[16][68];
    __shared__ float Bs[16][68];

    const int tid = threadIdx.x;
    const int tx = tid & 15, ty = tid >> 4;
    const int lrow = tid >> 2, lk = (tid & 3) * 4;

    float acc[4][4];
#pragma unroll
    for (int a = 0; a < 4; a++)
#pragma unroll
        for (int b = 0; b < 4; b++) acc[a][b] = 0.f;

    const float* aptr = x + (size_t)(m0 + lrow) * HDIM + lk;
    const float* bptr = W + (size_t)(n0 + lrow) * HDIM + lk;

    for (int k0 = 0; k0 < HDIM; k0 += 16) {
        float4 av = *(const float4*)(aptr + k0);
        float4 bv = *(const float4*)(bptr + k0);
        __syncthreads();
        As[lk + 0][lrow] = av.x; As[lk + 1][lrow] = av.y;
        As[lk + 2][lrow] = av.z; As[lk + 3][lrow] = av.w;
        Bs[lk + 0][lrow] = bv.x; Bs[lk + 1][lrow] = bv.y;
        Bs[lk + 2][lrow] = bv.z; Bs[lk + 3][lrow] = bv.w;
        __syncthreads();
#pragma unroll
        for (int kk = 0; kk < 16; kk++) {
            float4 a4 = *(const float4*)&As[kk][ty * 4];
            float4 b4 = *(const float4*)&Bs[kk][tx * 4];
            float a[4] = {a4.x, a4.y, a4.z, a4.w};
            float b[4] = {b4.x, b4.y, b4.z, b4.w};
#pragma unroll
            for (int ii = 0; ii < 4; ii++)
#pragma unroll
                for (int jj = 0; jj < 4; jj++)
                    acc[ii][jj] = fmaf(a[ii], b[jj], acc[ii][jj]);
        }
    }

    const int n = n0 + tx * 4;
    const int gate = n >> 10;
    const int sl = (n & 1023) >> 3;
    const int e0 = n & 7;
    float4 bias;
    bias.x = bih[n + 0] + bhh[n + 0];
    bias.y = bih[n + 1] + bhh[n + 1];
    bias.z = bih[n + 2] + bhh[n + 2];
    bias.w = bih[n + 3] + bhh[n + 3];

#pragma unroll
    for (int ii = 0; ii < 4; ii++) {
        int mloc = mloc0 + ty * 4 + ii;
        int iloc = dir ? (CHUNK - 1 - mloc) : mloc;
        float4 v;
        v.x = acc[ii][0] + bias.x;
        v.y = acc[ii][1] + bias.y;
        v.z = acc[ii][2] + bias.z;
        v.w = acc[ii][3] + bias.w;
        *(float4*)(xi_ring + ((size_t)(dir * 128 + sl) * CHUNK + iloc) * 32 + gate * 8 + e0) = v;
    }
}

// ---------------------------------------------------------------------------
// Persistent LSTM chunk: 256 blocks (dir = bx>>7, slice = bx&127).
// Each block owns h-elements [slice*8, slice*8+8): 32 gate rows of W_hh in
// VGPRs (128 floats/thread). Per step: poll flags for h[t-1], matvec, gates,
// write h slice (device-scope write-through) + release flag.
// ---------------------------------------------------------------------------
__global__ __launch_bounds__(256, 1) void lstm_chunk(
    const float* __restrict__ xi_ring, float* __restrict__ hall,
    unsigned* __restrict__ flags, float* __restrict__ cstate,
    const float* __restrict__ Whhf, const float* __restrict__ Whhb, int chunk) {
    extern __shared__ float smem[];
    float* hsh = smem;           // 1024 floats
    float* psum = smem + 1024;   // 256
    float* gsh = smem + 1280;    // 32

    const int tid = threadIdx.x;
    const int bx = blockIdx.x;
    const int dir = bx >> 7;
    const int slice = bx & 127;
    const int row32 = tid & 31;
    const int kc = tid >> 5;        // 0..7, k-window [kc*128, kc*128+128)
    const int gate = row32 >> 3;
    const int eloc = row32 & 7;

    const float* __restrict__ Whh = dir ? Whhb : Whhf;
    const int R = gate * HDIM + slice * 8 + eloc;

    float4 w4[32];
    {
        const float4* wsrc = (const float4*)(Whh + (size_t)R * HDIM + kc * 128);
#pragma unroll
        for (int j = 0; j < 32; j++) w4[j] = wsrc[j];
    }

    float creg = 0.f;
    if (chunk > 0 && tid < 8) creg = cstate[dir * HDIM + slice * 8 + tid];

    const size_t hbase = (size_t)dir * ((size_t)S_LEN * HDIM);

    for (int i = 0; i < CHUNK; i++) {
        const int t = chunk * CHUNK + i;

        float xi_v = 0.f;
        if (tid < 32) xi_v = xi_ring[((size_t)bx * CHUNK + (size_t)i) * 32 + tid];

        if (t == 0) {
            ((float4*)hsh)[tid] = make_float4(0.f, 0.f, 0.f, 0.f);
        } else {
            if (i > 0) {
                if (tid < 128) {
                    const unsigned want = (unsigned)t;  // producer of step t-1 wrote t
                    unsigned* fp = flags + ((size_t)dir * CHUNK + (i - 1)) * 128 + tid;
                    while (__hip_atomic_load(fp, __ATOMIC_ACQUIRE,
                                             __HIP_MEMORY_SCOPE_AGENT) != want) {}
                }
                __syncthreads();
                __threadfence();
            }
            ((float4*)hsh)[tid] =
                *((const float4*)(hall + hbase + (size_t)(t - 1) * HDIM) + tid);
        }
        __syncthreads();

        float acc = 0.f;
        const float4* h4p = ((const float4*)hsh) + kc * 32;
#pragma unroll
        for (int j = 0; j < 32; j++) {
            float4 h4 = h4p[j];
            acc = fmaf(w4[j].x, h4.x, acc);
            acc = fmaf(w4[j].y, h4.y, acc);
            acc = fmaf(w4[j].z, h4.z, acc);
            acc = fmaf(w4[j].w, h4.w, acc);
        }
        psum[kc * 32 + row32] = acc;
        __syncthreads();

        if (tid < 32) {
            float g = xi_v;
#pragma unroll
            for (int q = 0; q < 8; q++) g += psum[q * 32 + tid];
            gsh[tid] = g;
        }
        __syncthreads();

        if (tid < 8) {
            float gi = gsh[tid];
            float gf = gsh[8 + tid];
            float gg = gsh[16 + tid];
            float go = gsh[24 + tid];
            float iv = 1.f / (1.f + expf(-gi));
            float fv = 1.f / (1.f + expf(-gf));
            float gv = tanhf(gg);
            float ov = 1.f / (1.f + expf(-go));
            creg = fv * creg + iv * gv;
            float hv = ov * tanhf(creg);
            __hip_atomic_store(hall + hbase + (size_t)t * HDIM + slice * 8 + tid, hv,
                               __ATOMIC_RELAXED, __HIP_MEMORY_SCOPE_AGENT);
        }
        __syncthreads();  // drains vmcnt: h stores visible before flag
        if (tid == 0) {
            __hip_atomic_store(flags + ((size_t)dir * CHUNK + i) * 128 + slice,
                               (unsigned)(t + 1), __ATOMIC_RELEASE,
                               __HIP_MEMORY_SCOPE_AGENT);
        }
    }

    if (tid < 8) cstate[dir * HDIM + slice * 8 + tid] = creg;
}

// ---------------------------------------------------------------------------
// feats[t][tag] = [hf[t], hb_nat[8191-t]] . WdT[:, tag] + b_dense[tag]
// ---------------------------------------------------------------------------
__global__ __launch_bounds__(256) void feats_kernel(
    const float* __restrict__ hall, const float* __restrict__ WdT,
    const float* __restrict__ bd, float* __restrict__ feats) {
    __shared__ float hsh[2048];
    __shared__ float red[TTAG * 256];
    __shared__ float red2[192];

    const int t = blockIdx.x;
    const int tid = threadIdx.x;

    ((float4*)hsh)[tid] = ((const float4*)(hall + (size_t)t * HDIM))[tid];
    ((float4*)hsh)[256 + tid] =
        ((const float4*)(hall + (size_t)S_LEN * HDIM + (size_t)(S_LEN - 1 - t) * HDIM))[tid];
    __syncthreads();

    float acc[TTAG];
#pragma unroll
    for (int j = 0; j < TTAG; j++) acc[j] = 0.f;

    const int kbase = tid * 8;
#pragma unroll
    for (int q = 0; q < 8; q++) {
        float hv = hsh[kbase + q];
        const float4* wr = (const float4*)(WdT + (size_t)(kbase + q) * TTAG);
#pragma unroll
        for (int p = 0; p < 12; p++) {
            float4 w = wr[p];
            acc[p * 4 + 0] = fmaf(hv, w.x, acc[p * 4 + 0]);
            acc[p * 4 + 1] = fmaf(hv, w.y, acc[p * 4 + 1]);
            acc[p * 4 + 2] = fmaf(hv, w.z, acc[p * 4 + 2]);
            acc[p * 4 + 3] = fmaf(hv, w.w, acc[p * 4 + 3]);
        }
    }
#pragma unroll
    for (int j = 0; j < TTAG; j++) red[j * 256 + tid] = acc[j];
    __syncthreads();

    if (tid < 192) {
        int tag = tid >> 2, p = tid & 3;
        float s = 0.f;
#pragma unroll
        for (int q = 0; q < 64; q++) s += red[tag * 256 + p * 64 + q];
        red2[tag * 4 + p] = s;
    }
    __syncthreads();

    if (tid < TTAG) {
        feats[(size_t)t * TTAG + tid] =
            red2[tid * 4] + red2[tid * 4 + 1] + red2[tid * 4 + 2] + red2[tid * 4 + 3] + bd[tid];
    }
}

// ---------------------------------------------------------------------------
// Viterbi: single wave. Lane i (<48) holds trans row i in registers.
// Tournament argmax with contiguous-pair merges (first-index tie-break
// matching jnp.argmax). Lane 0 does terminal + backtrace.
// ---------------------------------------------------------------------------
__global__ __launch_bounds__(64, 1) void viterbi_kernel(
    const float* __restrict__ feats, const float* __restrict__ trans,
    unsigned char* __restrict__ bp, float* __restrict__ out) {
    const int lane = threadIdx.x;
    __shared__ float fvsh[64];

    float tr[TTAG];
#pragma unroll
    for (int j = 0; j < TTAG; j++)
        tr[j] = (lane < TTAG) ? trans[lane * TTAG + j] : -3.0e38f;

    float fv = (lane == START_TAG) ? 0.0f : -10000.0f;
    if (lane >= TTAG) fv = -3.0e38f;
    fvsh[lane] = fv;
    __syncthreads();

    for (int t = 0; t < S_LEN; t++) {
        float feat = (lane < TTAG) ? feats[(size_t)t * TTAG + lane] : 0.f;

        float fvv[TTAG];
#pragma unroll
        for (int jj = 0; jj < 12; jj++) {
            float4 v4 = *(const float4*)&fvsh[jj * 4];
            fvv[jj * 4 + 0] = v4.x; fvv[jj * 4 + 1] = v4.y;
            fvv[jj * 4 + 2] = v4.z; fvv[jj * 4 + 3] = v4.w;
        }

        float v[64];
        int ix[64];
#pragma unroll
        for (int j = 0; j < TTAG; j++) { v[j] = fvv[j] + tr[j]; ix[j] = j; }
#pragma unroll
        for (int j = TTAG; j < 64; j++) { v[j] = -3.0e38f; ix[j] = j; }

#pragma unroll
        for (int len = 64; len > 1; len >>= 1) {
#pragma unroll
            for (int q = 0; q < (len >> 1); q++) {
                bool tb = v[2 * q + 1] > v[2 * q];   // tie -> keep left (lower index)
                v[q] = tb ? v[2 * q + 1] : v[2 * q];
                ix[q] = tb ? ix[2 * q + 1] : ix[2 * q];
            }
        }

        if (lane < TTAG) bp[(size_t)t * TTAG + lane] = (unsigned char)ix[0];
        float nfv = (lane < TTAG) ? (v[0] + feat) : -3.0e38f;
        __syncthreads();
        fvsh[lane] = nfv;
        __syncthreads();
    }

    if (lane == 0) {
        float best = -3.4e38f;
        int bl = 0;
        for (int i = 0; i < TTAG; i++) {
            float term = fvsh[i] + trans[END_TAG * TTAG + i];
            if (term > best) { best = term; bl = i; }
        }
        out[0] = best;
        int tag = bl;
        out[1 + S_LEN - 1] = (float)tag;
        for (int t = S_LEN - 2; t >= 0; t--) {
            tag = bp[(size_t)(t + 1) * TTAG + tag];
            out[1 + t] = (float)tag;
        }
    }
}

// ---------------------------------------------------------------------------
extern "C" void kernel_launch(void* const* d_in, const int* in_sizes, int n_in,
                              void* d_out, int out_size, void* d_ws, size_t ws_size,
                              hipStream_t stream) {
    const float* sent = (const float*)d_in[0];
    const float* Wihf = (const float*)d_in[1];
    const float* Whhf = (const float*)d_in[2];
    const float* bihf = (const float*)d_in[3];
    const float* bhhf = (const float*)d_in[4];
    const float* Wihb = (const float*)d_in[5];
    const float* Whhb = (const float*)d_in[6];
    const float* bihb = (const float*)d_in[7];
    const float* bhhb = (const float*)d_in[8];
    const float* Wd = (const float*)d_in[9];
    const float* bd = (const float*)d_in[10];
    const float* trans = (const float*)d_in[11];
    float* out = (float*)d_out;

    float* ws = (float*)d_ws;
    float* xi_ring = ws;                                   // 256*1024*32 = 8,388,608 f
    float* hall = ws + 8388608;                            // 2*8192*1024 = 16,777,216 f
    unsigned* flags = (unsigned*)(hall + 16777216);        // 2*1024*128 = 262,144 u32
    float* cstate = (float*)(flags + 262144);              // 2048 f
    float* featsb = cstate + 2048;                         // 8192*48 = 393,216 f
    float* wdT = featsb + 393216;                          // 2048*48 = 98,304 f
    unsigned char* bp = (unsigned char*)(wdT + 98304);     // 8192*48 bytes

    wdt_kernel<<<dim3(384), dim3(256), 0, stream>>>(Wd, wdT);

    for (int c = 0; c < NCHUNK; c++) {
        gemm_xi<<<dim3(64, 16, 2), dim3(256), 0, stream>>>(
            sent, Wihf, Wihb, bihf, bhhf, bihb, bhhb, xi_ring, c);
        lstm_chunk<<<dim3(256), dim3(256), 65280, stream>>>(
            xi_ring, hall, flags, cstate, Whhf, Whhb, c);
    }

    feats_kernel<<<dim3(8192), dim3(256), 0, stream>>>(hall, wdT, bd, featsb);
    viterbi_kernel<<<dim3(1), dim3(64), 0, stream>>>(featsb, trans, bp, out);
}

// Round 2
// 50142.514 us; speedup vs baseline: 5.1933x; 5.1933x over previous
//
#include <hip/hip_runtime.h>

#define S_LEN 8192
#define HDIM 1024
#define TTAG 48
#define START_TAG 46
#define END_TAG 47
#define CHUNK 1024
#define NCHUNK 8

// ---------------------------------------------------------------------------
// Transpose W_dense (48 x 2048) -> WdT (2048 x 48) for coalesced feats loads
// ---------------------------------------------------------------------------
__global__ __launch_bounds__(256) void wdt_kernel(const float* __restrict__ Wd,
                                                  float* __restrict__ WdT) {
    int idx = blockIdx.x * 256 + threadIdx.x;
    if (idx < TTAG * 2048) {
        int tag = idx >> 11;       // / 2048
        int k = idx & 2047;
        WdT[(size_t)k * TTAG + tag] = Wd[idx];
    }
}

// ---------------------------------------------------------------------------
// xi GEMM: xi[m][n] = sum_k x[m][k] * W_ih[n][k] + (b_ih[n] + b_hh[n])
// Writes into permuted ring layout: xi_ring[(dir*128+slice)][i_local][32]
// where n = gate*1024 + slice*8 + e, within-slice index = gate*8 + e.
// ---------------------------------------------------------------------------
__global__ __launch_bounds__(256) void gemm_xi(
    const float* __restrict__ x,
    const float* __restrict__ Wf, const float* __restrict__ Wb,
    const float* __restrict__ bihf, const float* __restrict__ bhhf,
    const float* __restrict__ bihb, const float* __restrict__ bhhb,
    float* __restrict__ xi_ring, int chunk) {
    const int dir = blockIdx.z;
    const float* __restrict__ W = dir ? Wb : Wf;
    const float* __restrict__ bih = dir ? bihb : bihf;
    const float* __restrict__ bhh = dir ? bhhb : bhhf;

    const int mloc0 = blockIdx.y * 64;  // 0..960 within chunk slab
    const int m0 = (dir == 0 ? chunk * CHUNK : S_LEN - (chunk + 1) * CHUNK) + mloc0;
    const int n0 = blockIdx.x * 64;

    __shared__ float As[16][68];
    __shared__ float Bs[16][68];

    const int tid = threadIdx.x;
    const int tx = tid & 15, ty = tid >> 4;
    const int lrow = tid >> 2, lk = (tid & 3) * 4;

    float acc[4][4];
#pragma unroll
    for (int a = 0; a < 4; a++)
#pragma unroll
        for (int b = 0; b < 4; b++) acc[a][b] = 0.f;

    const float* aptr = x + (size_t)(m0 + lrow) * HDIM + lk;
    const float* bptr = W + (size_t)(n0 + lrow) * HDIM + lk;

    for (int k0 = 0; k0 < HDIM; k0 += 16) {
        float4 av = *(const float4*)(aptr + k0);
        float4 bv = *(const float4*)(bptr + k0);
        __syncthreads();
        As[lk + 0][lrow] = av.x; As[lk + 1][lrow] = av.y;
        As[lk + 2][lrow] = av.z; As[lk + 3][lrow] = av.w;
        Bs[lk + 0][lrow] = bv.x; Bs[lk + 1][lrow] = bv.y;
        Bs[lk + 2][lrow] = bv.z; Bs[lk + 3][lrow] = bv.w;
        __syncthreads();
#pragma unroll
        for (int kk = 0; kk < 16; kk++) {
            float4 a4 = *(const float4*)&As[kk][ty * 4];
            float4 b4 = *(const float4*)&Bs[kk][tx * 4];
            float a[4] = {a4.x, a4.y, a4.z, a4.w};
            float b[4] = {b4.x, b4.y, b4.z, b4.w};
#pragma unroll
            for (int ii = 0; ii < 4; ii++)
#pragma unroll
                for (int jj = 0; jj < 4; jj++)
                    acc[ii][jj] = fmaf(a[ii], b[jj], acc[ii][jj]);
        }
    }

    const int n = n0 + tx * 4;
    const int gate = n >> 10;
    const int sl = (n & 1023) >> 3;
    const int e0 = n & 7;
    float4 bias;
    bias.x = bih[n + 0] + bhh[n + 0];
    bias.y = bih[n + 1] + bhh[n + 1];
    bias.z = bih[n + 2] + bhh[n + 2];
    bias.w = bih[n + 3] + bhh[n + 3];

#pragma unroll
    for (int ii = 0; ii < 4; ii++) {
        int mloc = mloc0 + ty * 4 + ii;
        int iloc = dir ? (CHUNK - 1 - mloc) : mloc;
        float4 v;
        v.x = acc[ii][0] + bias.x;
        v.y = acc[ii][1] + bias.y;
        v.z = acc[ii][2] + bias.z;
        v.w = acc[ii][3] + bias.w;
        *(float4*)(xi_ring + ((size_t)(dir * 128 + sl) * CHUNK + iloc) * 32 + gate * 8 + e0) = v;
    }
}

// ---------------------------------------------------------------------------
// Persistent LSTM chunk: 256 blocks (dir = bx>>7, slice = bx&127), 1 block/CU.
// Sync pattern: ALL cross-block traffic is LLC-direct relaxed agent atomics.
// No acquire/release, no threadfence -> no per-step L1/L2 invalidate storms.
//  - producer: h stores = relaxed agent (sc1 write-through to LLC);
//    __syncthreads drains vmcnt(0); flag store = relaxed agent.
//  - consumer: spin on flags with relaxed agent loads (read LLC directly);
//    then gather h(t-1) with relaxed agent dword loads (bypass stale L2).
// ---------------------------------------------------------------------------
__global__ __launch_bounds__(256, 1) void lstm_chunk(
    const float* __restrict__ xi_ring, float* __restrict__ hall,
    unsigned* __restrict__ flags, float* __restrict__ cstate,
    const float* __restrict__ Whhf, const float* __restrict__ Whhb, int chunk) {
    extern __shared__ float smem[];
    float* hsh = smem;           // 1024 floats
    float* psum = smem + 1024;   // 256
    float* gsh = smem + 1280;    // 32

    const int tid = threadIdx.x;
    const int bx = blockIdx.x;
    const int dir = bx >> 7;
    const int slice = bx & 127;
    const int row32 = tid & 31;
    const int kc = tid >> 5;        // 0..7, k-window [kc*128, kc*128+128)
    const int gate = row32 >> 3;
    const int eloc = row32 & 7;

    const float* __restrict__ Whh = dir ? Whhb : Whhf;
    const int R = gate * HDIM + slice * 8 + eloc;

    float4 w4[32];
    {
        const float4* wsrc = (const float4*)(Whh + (size_t)R * HDIM + kc * 128);
#pragma unroll
        for (int j = 0; j < 32; j++) w4[j] = wsrc[j];
    }

    float creg = 0.f;
    if (chunk > 0 && tid < 8) creg = cstate[dir * HDIM + slice * 8 + tid];

    const size_t hbase = (size_t)dir * ((size_t)S_LEN * HDIM);

    for (int i = 0; i < CHUNK; i++) {
        const int t = chunk * CHUNK + i;

        float xi_v = 0.f;
        if (tid < 32) xi_v = xi_ring[((size_t)bx * CHUNK + (size_t)i) * 32 + tid];

        if (t == 0) {
            ((float4*)hsh)[tid] = make_float4(0.f, 0.f, 0.f, 0.f);
        } else {
            if (i > 0) {
                if (tid < 128) {
                    const unsigned want = (unsigned)t;  // producer of step t-1 wrote t
                    unsigned* fp = flags + ((size_t)dir * CHUNK + (i - 1)) * 128 + tid;
                    while (__hip_atomic_load(fp, __ATOMIC_RELAXED,
                                             __HIP_MEMORY_SCOPE_AGENT) != want) {}
                }
                __syncthreads();
            }
            // LLC-direct gather of h(t-1); coalesced dword loads, 4 per thread.
            const float* hrow = hall + hbase + (size_t)(t - 1) * HDIM;
            float h0 = __hip_atomic_load(hrow + tid, __ATOMIC_RELAXED,
                                         __HIP_MEMORY_SCOPE_AGENT);
            float h1 = __hip_atomic_load(hrow + 256 + tid, __ATOMIC_RELAXED,
                                         __HIP_MEMORY_SCOPE_AGENT);
            float h2 = __hip_atomic_load(hrow + 512 + tid, __ATOMIC_RELAXED,
                                         __HIP_MEMORY_SCOPE_AGENT);
            float h3 = __hip_atomic_load(hrow + 768 + tid, __ATOMIC_RELAXED,
                                         __HIP_MEMORY_SCOPE_AGENT);
            hsh[tid] = h0;
            hsh[256 + tid] = h1;
            hsh[512 + tid] = h2;
            hsh[768 + tid] = h3;
        }
        __syncthreads();

        float acc = 0.f;
        const float4* h4p = ((const float4*)hsh) + kc * 32;
#pragma unroll
        for (int j = 0; j < 32; j++) {
            float4 h4 = h4p[j];
            acc = fmaf(w4[j].x, h4.x, acc);
            acc = fmaf(w4[j].y, h4.y, acc);
            acc = fmaf(w4[j].z, h4.z, acc);
            acc = fmaf(w4[j].w, h4.w, acc);
        }
        psum[kc * 32 + row32] = acc;
        __syncthreads();

        if (tid < 32) {
            float g = xi_v;
#pragma unroll
            for (int q = 0; q < 8; q++) g += psum[q * 32 + tid];
            gsh[tid] = g;
        }
        __syncthreads();

        if (tid < 8) {
            float gi = gsh[tid];
            float gf = gsh[8 + tid];
            float gg = gsh[16 + tid];
            float go = gsh[24 + tid];
            float iv = 1.f / (1.f + expf(-gi));
            float fv = 1.f / (1.f + expf(-gf));
            float gv = tanhf(gg);
            float ov = 1.f / (1.f + expf(-go));
            creg = fv * creg + iv * gv;
            float hv = ov * tanhf(creg);
            __hip_atomic_store(hall + hbase + (size_t)t * HDIM + slice * 8 + tid, hv,
                               __ATOMIC_RELAXED, __HIP_MEMORY_SCOPE_AGENT);
        }
        __syncthreads();  // drains vmcnt(0): h stores are at LLC before flag
        if (tid == 0) {
            __hip_atomic_store(flags + ((size_t)dir * CHUNK + i) * 128 + slice,
                               (unsigned)(t + 1), __ATOMIC_RELAXED,
                               __HIP_MEMORY_SCOPE_AGENT);
        }
    }

    if (tid < 8) cstate[dir * HDIM + slice * 8 + tid] = creg;
}

// ---------------------------------------------------------------------------
// feats[t][tag] = [hf[t], hb_nat[8191-t]] . WdT[:, tag] + b_dense[tag]
// ---------------------------------------------------------------------------
__global__ __launch_bounds__(256) void feats_kernel(
    const float* __restrict__ hall, const float* __restrict__ WdT,
    const float* __restrict__ bd, float* __restrict__ feats) {
    __shared__ float hsh[2048];
    __shared__ float red[TTAG * 256];
    __shared__ float red2[192];

    const int t = blockIdx.x;
    const int tid = threadIdx.x;

    ((float4*)hsh)[tid] = ((const float4*)(hall + (size_t)t * HDIM))[tid];
    ((float4*)hsh)[256 + tid] =
        ((const float4*)(hall + (size_t)S_LEN * HDIM + (size_t)(S_LEN - 1 - t) * HDIM))[tid];
    __syncthreads();

    float acc[TTAG];
#pragma unroll
    for (int j = 0; j < TTAG; j++) acc[j] = 0.f;

    const int kbase = tid * 8;
#pragma unroll
    for (int q = 0; q < 8; q++) {
        float hv = hsh[kbase + q];
        const float4* wr = (const float4*)(WdT + (size_t)(kbase + q) * TTAG);
#pragma unroll
        for (int p = 0; p < 12; p++) {
            float4 w = wr[p];
            acc[p * 4 + 0] = fmaf(hv, w.x, acc[p * 4 + 0]);
            acc[p * 4 + 1] = fmaf(hv, w.y, acc[p * 4 + 1]);
            acc[p * 4 + 2] = fmaf(hv, w.z, acc[p * 4 + 2]);
            acc[p * 4 + 3] = fmaf(hv, w.w, acc[p * 4 + 3]);
        }
    }
#pragma unroll
    for (int j = 0; j < TTAG; j++) red[j * 256 + tid] = acc[j];
    __syncthreads();

    if (tid < 192) {
        int tag = tid >> 2, p = tid & 3;
        float s = 0.f;
#pragma unroll
        for (int q = 0; q < 64; q++) s += red[tag * 256 + p * 64 + q];
        red2[tag * 4 + p] = s;
    }
    __syncthreads();

    if (tid < TTAG) {
        feats[(size_t)t * TTAG + tid] =
            red2[tid * 4] + red2[tid * 4 + 1] + red2[tid * 4 + 2] + red2[tid * 4 + 3] + bd[tid];
    }
}

// ---------------------------------------------------------------------------
// Viterbi: single wave. Lane i (<48) holds trans row i in registers.
// Tournament argmax with contiguous-pair merges (first-index tie-break
// matching jnp.argmax). Lane 0 does terminal + backtrace.
// ---------------------------------------------------------------------------
__global__ __launch_bounds__(64, 1) void viterbi_kernel(
    const float* __restrict__ feats, const float* __restrict__ trans,
    unsigned char* __restrict__ bp, float* __restrict__ out) {
    const int lane = threadIdx.x;
    __shared__ float fvsh[64];

    float tr[TTAG];
#pragma unroll
    for (int j = 0; j < TTAG; j++)
        tr[j] = (lane < TTAG) ? trans[lane * TTAG + j] : -3.0e38f;

    float fv = (lane == START_TAG) ? 0.0f : -10000.0f;
    if (lane >= TTAG) fv = -3.0e38f;
    fvsh[lane] = fv;
    __syncthreads();

    for (int t = 0; t < S_LEN; t++) {
        float feat = (lane < TTAG) ? feats[(size_t)t * TTAG + lane] : 0.f;

        float fvv[TTAG];
#pragma unroll
        for (int jj = 0; jj < 12; jj++) {
            float4 v4 = *(const float4*)&fvsh[jj * 4];
            fvv[jj * 4 + 0] = v4.x; fvv[jj * 4 + 1] = v4.y;
            fvv[jj * 4 + 2] = v4.z; fvv[jj * 4 + 3] = v4.w;
        }

        float v[64];
        int ix[64];
#pragma unroll
        for (int j = 0; j < TTAG; j++) { v[j] = fvv[j] + tr[j]; ix[j] = j; }
#pragma unroll
        for (int j = TTAG; j < 64; j++) { v[j] = -3.0e38f; ix[j] = j; }

#pragma unroll
        for (int len = 64; len > 1; len >>= 1) {
#pragma unroll
            for (int q = 0; q < (len >> 1); q++) {
                bool tb = v[2 * q + 1] > v[2 * q];   // tie -> keep left (lower index)
                v[q] = tb ? v[2 * q + 1] : v[2 * q];
                ix[q] = tb ? ix[2 * q + 1] : ix[2 * q];
            }
        }

        if (lane < TTAG) bp[(size_t)t * TTAG + lane] = (unsigned char)ix[0];
        float nfv = (lane < TTAG) ? (v[0] + feat) : -3.0e38f;
        __syncthreads();
        fvsh[lane] = nfv;
        __syncthreads();
    }

    if (lane == 0) {
        float best = -3.4e38f;
        int bl = 0;
        for (int i = 0; i < TTAG; i++) {
            float term = fvsh[i] + trans[END_TAG * TTAG + i];
            if (term > best) { best = term; bl = i; }
        }
        out[0] = best;
        int tag = bl;
        out[1 + S_LEN - 1] = (float)tag;
        for (int t = S_LEN - 2; t >= 0; t--) {
            tag = bp[(size_t)(t + 1) * TTAG + tag];
            out[1 + t] = (float)tag;
        }
    }
}

// ---------------------------------------------------------------------------
extern "C" void kernel_launch(void* const* d_in, const int* in_sizes, int n_in,
                              void* d_out, int out_size, void* d_ws, size_t ws_size,
                              hipStream_t stream) {
    const float* sent = (const float*)d_in[0];
    const float* Wihf = (const float*)d_in[1];
    const float* Whhf = (const float*)d_in[2];
    const float* bihf = (const float*)d_in[3];
    const float* bhhf = (const float*)d_in[4];
    const float* Wihb = (const float*)d_in[5];
    const float* Whhb = (const float*)d_in[6];
    const float* bihb = (const float*)d_in[7];
    const float* bhhb = (const float*)d_in[8];
    const float* Wd = (const float*)d_in[9];
    const float* bd = (const float*)d_in[10];
    const float* trans = (const float*)d_in[11];
    float* out = (float*)d_out;

    float* ws = (float*)d_ws;
    float* xi_ring = ws;                                   // 256*1024*32 = 8,388,608 f
    float* hall = ws + 8388608;                            // 2*8192*1024 = 16,777,216 f
    unsigned* flags = (unsigned*)(hall + 16777216);        // 2*1024*128 = 262,144 u32
    float* cstate = (float*)(flags + 262144);              // 2048 f
    float* featsb = cstate + 2048;                         // 8192*48 = 393,216 f
    float* wdT = featsb + 393216;                          // 2048*48 = 98,304 f
    unsigned char* bp = (unsigned char*)(wdT + 98304);     // 8192*48 bytes

    wdt_kernel<<<dim3(384), dim3(256), 0, stream>>>(Wd, wdT);

    for (int c = 0; c < NCHUNK; c++) {
        gemm_xi<<<dim3(64, 16, 2), dim3(256), 0, stream>>>(
            sent, Wihf, Wihb, bihf, bhhf, bihb, bhhb, xi_ring, c);
        lstm_chunk<<<dim3(256), dim3(256), 65280, stream>>>(
            xi_ring, hall, flags, cstate, Whhf, Whhb, c);
    }

    feats_kernel<<<dim3(8192), dim3(256), 0, stream>>>(hall, wdT, bd, featsb);
    viterbi_kernel<<<dim3(1), dim3(64), 0, stream>>>(featsb, trans, bp, out);
}

// Round 4
// 30192.328 us; speedup vs baseline: 8.6249x; 1.6608x over previous
//
#include <hip/hip_runtime.h>

#define S_LEN 8192
#define HDIM 1024
#define TTAG 48
#define START_TAG 46
#define END_TAG 47
#define CHUNK 1024
#define NCHUNK 8
#define NSLOT 16   // h-record ring slots (producer/consumer skew <=1; ample)

typedef float f4 __attribute__((ext_vector_type(4)));

// Opaque 8x16B weight load (prevents compiler from sinking/remat the loads;
// forces the 128 weight floats per thread to stay VGPR-resident).
#define ASM_LD8(o0,o1,o2,o3,o4,o5,o6,o7,p)                                    \
  asm volatile("global_load_dwordx4 %0, %8, off\n\t"                          \
               "global_load_dwordx4 %1, %8, off offset:16\n\t"                \
               "global_load_dwordx4 %2, %8, off offset:32\n\t"                \
               "global_load_dwordx4 %3, %8, off offset:48\n\t"                \
               "global_load_dwordx4 %4, %8, off offset:64\n\t"                \
               "global_load_dwordx4 %5, %8, off offset:80\n\t"                \
               "global_load_dwordx4 %6, %8, off offset:96\n\t"                \
               "global_load_dwordx4 %7, %8, off offset:112\n\t"               \
               "s_waitcnt vmcnt(0)"                                           \
               : "=v"(o0),"=v"(o1),"=v"(o2),"=v"(o3),                         \
                 "=v"(o4),"=v"(o5),"=v"(o6),"=v"(o7)                          \
               : "v"(p) : "memory")

// LLC-direct (bypass L1/L2) 48-B record probe: three 16-B atoms, one wait.
#define ASM_POLL3(a0,a1,a2,p)                                                 \
  asm volatile("global_load_dwordx4 %0, %3, off sc0 sc1\n\t"                  \
               "global_load_dwordx4 %1, %3, off offset:16 sc0 sc1\n\t"        \
               "global_load_dwordx4 %2, %3, off offset:32 sc0 sc1\n\t"        \
               "s_waitcnt vmcnt(0)"                                           \
               : "=v"(a0),"=v"(a1),"=v"(a2) : "v"(p) : "memory")

// LLC write-through 16-B store (single transaction -> seq+data atomic).
#define ASM_ST_SC(p,v4)                                                       \
  asm volatile("global_store_dwordx4 %0, %1, off sc0 sc1"                     \
               :: "v"(p), "v"(v4) : "memory")

__device__ __forceinline__ void fma4(const f4 wv, const f4 hv, float& acc) {
    acc = fmaf(wv.x, hv.x, acc);
    acc = fmaf(wv.y, hv.y, acc);
    acc = fmaf(wv.z, hv.z, acc);
    acc = fmaf(wv.w, hv.w, acc);
}

// ---------------------------------------------------------------------------
// Transpose W_dense (48 x 2048) -> WdT (2048 x 48)
// ---------------------------------------------------------------------------
__global__ __launch_bounds__(256) void wdt_kernel(const float* __restrict__ Wd,
                                                  float* __restrict__ WdT) {
    int idx = blockIdx.x * 256 + threadIdx.x;
    if (idx < TTAG * 2048) {
        int tag = idx >> 11;
        int k = idx & 2047;
        WdT[(size_t)k * TTAG + tag] = Wd[idx];
    }
}

// ---------------------------------------------------------------------------
// xi GEMM (unchanged from round 2)
// ---------------------------------------------------------------------------
__global__ __launch_bounds__(256) void gemm_xi(
    const float* __restrict__ x,
    const float* __restrict__ Wf, const float* __restrict__ Wb,
    const float* __restrict__ bihf, const float* __restrict__ bhhf,
    const float* __restrict__ bihb, const float* __restrict__ bhhb,
    float* __restrict__ xi_ring, int chunk) {
    const int dir = blockIdx.z;
    const float* __restrict__ W = dir ? Wb : Wf;
    const float* __restrict__ bih = dir ? bihb : bihf;
    const float* __restrict__ bhh = dir ? bhhb : bhhf;

    const int mloc0 = blockIdx.y * 64;
    const int m0 = (dir == 0 ? chunk * CHUNK : S_LEN - (chunk + 1) * CHUNK) + mloc0;
    const int n0 = blockIdx.x * 64;

    __shared__ float As[16][68];
    __shared__ float Bs[16][68];

    const int tid = threadIdx.x;
    const int tx = tid & 15, ty = tid >> 4;
    const int lrow = tid >> 2, lk = (tid & 3) * 4;

    float acc[4][4];
#pragma unroll
    for (int a = 0; a < 4; a++)
#pragma unroll
        for (int b = 0; b < 4; b++) acc[a][b] = 0.f;

    const float* aptr = x + (size_t)(m0 + lrow) * HDIM + lk;
    const float* bptr = W + (size_t)(n0 + lrow) * HDIM + lk;

    for (int k0 = 0; k0 < HDIM; k0 += 16) {
        float4 av = *(const float4*)(aptr + k0);
        float4 bv = *(const float4*)(bptr + k0);
        __syncthreads();
        As[lk + 0][lrow] = av.x; As[lk + 1][lrow] = av.y;
        As[lk + 2][lrow] = av.z; As[lk + 3][lrow] = av.w;
        Bs[lk + 0][lrow] = bv.x; Bs[lk + 1][lrow] = bv.y;
        Bs[lk + 2][lrow] = bv.z; Bs[lk + 3][lrow] = bv.w;
        __syncthreads();
#pragma unroll
        for (int kk = 0; kk < 16; kk++) {
            float4 a4 = *(const float4*)&As[kk][ty * 4];
            float4 b4 = *(const float4*)&Bs[kk][tx * 4];
            float a[4] = {a4.x, a4.y, a4.z, a4.w};
            float b[4] = {b4.x, b4.y, b4.z, b4.w};
#pragma unroll
            for (int ii = 0; ii < 4; ii++)
#pragma unroll
                for (int jj = 0; jj < 4; jj++)
                    acc[ii][jj] = fmaf(a[ii], b[jj], acc[ii][jj]);
        }
    }

    const int n = n0 + tx * 4;
    const int gate = n >> 10;
    const int sl = (n & 1023) >> 3;
    const int e0 = n & 7;
    float4 bias;
    bias.x = bih[n + 0] + bhh[n + 0];
    bias.y = bih[n + 1] + bhh[n + 1];
    bias.z = bih[n + 2] + bhh[n + 2];
    bias.w = bih[n + 3] + bhh[n + 3];

#pragma unroll
    for (int ii = 0; ii < 4; ii++) {
        int mloc = mloc0 + ty * 4 + ii;
        int iloc = dir ? (CHUNK - 1 - mloc) : mloc;
        float4 v;
        v.x = acc[ii][0] + bias.x;
        v.y = acc[ii][1] + bias.y;
        v.z = acc[ii][2] + bias.z;
        v.w = acc[ii][3] + bias.w;
        *(float4*)(xi_ring + ((size_t)(dir * 128 + sl) * CHUNK + iloc) * 32 + gate * 8 + e0) = v;
    }
}

// ---------------------------------------------------------------------------
// Persistent LSTM chunk. 256 blocks (dir=bx>>7, slice=bx&127), 1 block/CU.
// Weights VGPR-pinned via asm loads. Cross-block handoff = self-validating
// 48-B records in an LLC ring: {h0,h1,h2,seq}{h3,h4,h5,seq}{h6,h7,h7,seq}.
// One LLC round trip per step (poll==gather); no producer drain needed.
// ---------------------------------------------------------------------------
__global__ __launch_bounds__(256, 1) void lstm_chunk(
    const float* __restrict__ xi_ring, float* __restrict__ hall,
    float* __restrict__ hrec, float* __restrict__ cstate,
    const float* __restrict__ Whhf, const float* __restrict__ Whhb, int chunk) {
    __shared__ float hsh[HDIM];
    __shared__ float psum[256];

    const int tid = threadIdx.x;
    const int bx = blockIdx.x;
    const int dir = bx >> 7;
    const int slice = bx & 127;
    const int row32 = tid & 31;
    const int kc = tid >> 5;        // k-window [kc*128, kc*128+128)
    const int gate = row32 >> 3;
    const int eloc = row32 & 7;

    const float* __restrict__ Whh = dir ? Whhb : Whhf;
    const int R = gate * HDIM + slice * 8 + eloc;
    const float* wsrc = Whh + (size_t)R * HDIM + kc * 128;

    f4 w00,w01,w02,w03,w04,w05,w06,w07,w08,w09,w10,w11,w12,w13,w14,w15;
    f4 w16,w17,w18,w19,w20,w21,w22,w23,w24,w25,w26,w27,w28,w29,w30,w31;
    ASM_LD8(w00,w01,w02,w03,w04,w05,w06,w07, wsrc);
    ASM_LD8(w08,w09,w10,w11,w12,w13,w14,w15, wsrc + 32);
    ASM_LD8(w16,w17,w18,w19,w20,w21,w22,w23, wsrc + 64);
    ASM_LD8(w24,w25,w26,w27,w28,w29,w30,w31, wsrc + 96);

    float creg = 0.f;
    if (chunk > 0 && tid < 8) creg = cstate[dir * HDIM + slice * 8 + tid];

    const size_t hbase = (size_t)dir * ((size_t)S_LEN * HDIM);
    f4* hsh4 = (f4*)hsh;

    for (int i = 0; i < CHUNK; i++) {
        const int t = chunk * CHUNK + i;

        float xi_v = 0.f;
        if (tid < 32) xi_v = xi_ring[((size_t)bx * CHUNK + (size_t)i) * 32 + tid];

        if (t == 0) {
            f4 z; z.x = 0.f; z.y = 0.f; z.z = 0.f; z.w = 0.f;
            hsh4[tid] = z;  // 256 threads x 4 = 1024 floats
        } else if (tid < 128) {
            const int j = (t - 1) & (NSLOT - 1);
            const float* rp = hrec + ((size_t)(dir * NSLOT + j) * 128 + tid) * 12;
            f4 a0, a1, a2;
            do {
                ASM_POLL3(a0, a1, a2, rp);
            } while (__float_as_int(a0.w) != t || __float_as_int(a1.w) != t ||
                     __float_as_int(a2.w) != t);
            f4 u, v;
            u.x = a0.x; u.y = a0.y; u.z = a0.z; u.w = a1.x;
            v.x = a1.y; v.y = a1.z; v.z = a2.x; v.w = a2.y;
            hsh4[2 * tid] = u;
            hsh4[2 * tid + 1] = v;
        }
        __syncthreads();

        float acc0 = 0.f, acc1 = 0.f, acc2 = 0.f, acc3 = 0.f;
        const f4* h4p = (const f4*)hsh + kc * 32;
        fma4(w00, h4p[0],  acc0); fma4(w01, h4p[1],  acc1);
        fma4(w02, h4p[2],  acc2); fma4(w03, h4p[3],  acc3);
        fma4(w04, h4p[4],  acc0); fma4(w05, h4p[5],  acc1);
        fma4(w06, h4p[6],  acc2); fma4(w07, h4p[7],  acc3);
        fma4(w08, h4p[8],  acc0); fma4(w09, h4p[9],  acc1);
        fma4(w10, h4p[10], acc2); fma4(w11, h4p[11], acc3);
        fma4(w12, h4p[12], acc0); fma4(w13, h4p[13], acc1);
        fma4(w14, h4p[14], acc2); fma4(w15, h4p[15], acc3);
        fma4(w16, h4p[16], acc0); fma4(w17, h4p[17], acc1);
        fma4(w18, h4p[18], acc2); fma4(w19, h4p[19], acc3);
        fma4(w20, h4p[20], acc0); fma4(w21, h4p[21], acc1);
        fma4(w22, h4p[22], acc2); fma4(w23, h4p[23], acc3);
        fma4(w24, h4p[24], acc0); fma4(w25, h4p[25], acc1);
        fma4(w26, h4p[26], acc2); fma4(w27, h4p[27], acc3);
        fma4(w28, h4p[28], acc0); fma4(w29, h4p[29], acc1);
        fma4(w30, h4p[30], acc2); fma4(w31, h4p[31], acc3);
        psum[kc * 32 + row32] = (acc0 + acc1) + (acc2 + acc3);
        __syncthreads();

        if (tid < 64) {  // wave 0: reduce + gates + publish
            const int l5 = tid & 31;
            float g = xi_v;
#pragma unroll
            for (int q = 0; q < 8; q++) g += psum[q * 32 + l5];
            const int e = tid & 7;
            float gI = __shfl(g, e);
            float gF = __shfl(g, 8 + e);
            float gG = __shfl(g, 16 + e);
            float gO = __shfl(g, 24 + e);
            float iv = 1.f / (1.f + expf(-gI));
            float fv = 1.f / (1.f + expf(-gF));
            float gv = tanhf(gG);
            float ov = 1.f / (1.f + expf(-gO));
            float cn = fv * creg + iv * gv;
            creg = cn;  // only lanes 0-7 matter
            float hv = ov * tanhf(cn);

            float h0 = __shfl(hv, 0), h1 = __shfl(hv, 1), h2 = __shfl(hv, 2);
            float h3 = __shfl(hv, 3), h4 = __shfl(hv, 4), h5 = __shfl(hv, 5);
            float h6 = __shfl(hv, 6), h7 = __shfl(hv, 7);

            if (tid < 8)
                hall[hbase + (size_t)t * HDIM + slice * 8 + tid] = hv;
            if (tid < 3) {
                f4 av;
                av.x = (tid == 0) ? h0 : (tid == 1) ? h3 : h6;
                av.y = (tid == 0) ? h1 : (tid == 1) ? h4 : h7;
                av.z = (tid == 0) ? h2 : (tid == 1) ? h5 : h7;
                av.w = __int_as_float(t + 1);
                float* sp = hrec +
                    ((size_t)(dir * NSLOT + (t & (NSLOT - 1))) * 128 + slice) * 12 +
                    tid * 4;
                ASM_ST_SC(sp, av);
            }
        }
        // no barrier needed here: next-iter hsh writes happen after this
        // iter's psum barrier; wave0's psum reads finish before it rejoins.
    }

    if (tid < 8) cstate[dir * HDIM + slice * 8 + tid] = creg;
}

// ---------------------------------------------------------------------------
// feats[t][tag] = [hf[t], hb_nat[8191-t]] . WdT[:, tag] + b_dense[tag]
// ---------------------------------------------------------------------------
__global__ __launch_bounds__(256) void feats_kernel(
    const float* __restrict__ hall, const float* __restrict__ WdT,
    const float* __restrict__ bd, float* __restrict__ feats) {
    __shared__ float hsh[2048];
    __shared__ float red[TTAG * 256];
    __shared__ float red2[192];

    const int t = blockIdx.x;
    const int tid = threadIdx.x;

    ((float4*)hsh)[tid] = ((const float4*)(hall + (size_t)t * HDIM))[tid];
    ((float4*)hsh)[256 + tid] =
        ((const float4*)(hall + (size_t)S_LEN * HDIM + (size_t)(S_LEN - 1 - t) * HDIM))[tid];
    __syncthreads();

    float acc[TTAG];
#pragma unroll
    for (int j = 0; j < TTAG; j++) acc[j] = 0.f;

    const int kbase = tid * 8;
#pragma unroll
    for (int q = 0; q < 8; q++) {
        float hv = hsh[kbase + q];
        const float4* wr = (const float4*)(WdT + (size_t)(kbase + q) * TTAG);
#pragma unroll
        for (int p = 0; p < 12; p++) {
            float4 w = wr[p];
            acc[p * 4 + 0] = fmaf(hv, w.x, acc[p * 4 + 0]);
            acc[p * 4 + 1] = fmaf(hv, w.y, acc[p * 4 + 1]);
            acc[p * 4 + 2] = fmaf(hv, w.z, acc[p * 4 + 2]);
            acc[p * 4 + 3] = fmaf(hv, w.w, acc[p * 4 + 3]);
        }
    }
#pragma unroll
    for (int j = 0; j < TTAG; j++) red[j * 256 + tid] = acc[j];
    __syncthreads();

    if (tid < 192) {
        int tag = tid >> 2, p = tid & 3;
        float s = 0.f;
#pragma unroll
        for (int q = 0; q < 64; q++) s += red[tag * 256 + p * 64 + q];
        red2[tag * 4 + p] = s;
    }
    __syncthreads();

    if (tid < TTAG) {
        feats[(size_t)t * TTAG + tid] =
            red2[tid * 4] + red2[tid * 4 + 1] + red2[tid * 4 + 2] + red2[tid * 4 + 3] + bd[tid];
    }
}

// ---------------------------------------------------------------------------
// Viterbi, single wave. Feats double-buffered through LDS in 64-step tiles
// (prefetched into registers; no global load on the recurrence chain).
// Backtrace: row loads are tag-independent -> blocked loads + __shfl select.
// ---------------------------------------------------------------------------
__global__ __launch_bounds__(64, 1) void viterbi_kernel(
    const float* __restrict__ feats, const float* __restrict__ trans,
    unsigned char* __restrict__ bp, float* __restrict__ out) {
    __shared__ float fbuf[2][64 * TTAG];
    __shared__ float fvsh[64];
    const int lane = threadIdx.x;

    float tr[TTAG];
#pragma unroll
    for (int j = 0; j < TTAG; j++)
        tr[j] = (lane < TTAG) ? trans[lane * TTAG + j] : -3.0e38f;

    fvsh[lane] = (lane == START_TAG) ? 0.0f
               : (lane < TTAG) ? -10000.0f : -3.0e38f;

    const f4* f4src = (const f4*)feats;  // 64*48 floats = 768 f4 per tile
    f4 nx[12];
#pragma unroll
    for (int q = 0; q < 12; q++) nx[q] = f4src[q * 64 + lane];
    {
        f4* nb = (f4*)fbuf[0];
#pragma unroll
        for (int q = 0; q < 12; q++) nb[q * 64 + lane] = nx[q];
    }
    __syncthreads();

    for (int blk = 0; blk < 128; blk++) {
        const float* fb = fbuf[blk & 1];
        if (blk < 127) {
#pragma unroll
            for (int q = 0; q < 12; q++)
                nx[q] = f4src[(size_t)(blk + 1) * 768 + q * 64 + lane];
        }

        for (int step = 0; step < 64; step++) {
            const int t = blk * 64 + step;
            float feat = (lane < TTAG) ? fb[step * TTAG + lane] : 0.f;

            float fvv[TTAG];
#pragma unroll
            for (int jj = 0; jj < 12; jj++) {
                f4 v4 = *(const f4*)&fvsh[jj * 4];
                fvv[jj * 4 + 0] = v4.x; fvv[jj * 4 + 1] = v4.y;
                fvv[jj * 4 + 2] = v4.z; fvv[jj * 4 + 3] = v4.w;
            }

            float v[64];
            int ix[64];
#pragma unroll
            for (int j = 0; j < TTAG; j++) { v[j] = fvv[j] + tr[j]; ix[j] = j; }
#pragma unroll
            for (int j = TTAG; j < 64; j++) { v[j] = -3.0e38f; ix[j] = j; }

#pragma unroll
            for (int len = 64; len > 1; len >>= 1) {
#pragma unroll
                for (int q = 0; q < (len >> 1); q++) {
                    bool tb = v[2 * q + 1] > v[2 * q];  // tie -> keep lower index
                    v[q] = tb ? v[2 * q + 1] : v[2 * q];
                    ix[q] = tb ? ix[2 * q + 1] : ix[2 * q];
                }
            }

            if (lane < TTAG) bp[(size_t)t * TTAG + lane] = (unsigned char)ix[0];
            float nfv = (lane < TTAG) ? (v[0] + feat) : -3.0e38f;
            fvsh[lane] = nfv;  // single wave: LDS FIFO orders vs next reads
        }

        if (blk < 127) {
            f4* nb = (f4*)fbuf[(blk + 1) & 1];
#pragma unroll
            for (int q = 0; q < 12; q++) nb[q * 64 + lane] = nx[q];
        }
        __syncthreads();
    }

    // terminal
    float term = (lane < TTAG) ? fvsh[lane] + trans[END_TAG * TTAG + lane]
                               : -3.0e38f;
    __syncthreads();
    fvsh[lane] = term;
    __syncthreads();
    int bl = 0;
    if (lane == 0) {
        float best = -3.4e38f;
        for (int i = 0; i < TTAG; i++) {
            if (fvsh[i] > best) { best = fvsh[i]; bl = i; }
        }
        out[0] = best;
    }
    int tag = __shfl(bl, 0);
    if (lane == 0) out[1 + S_LEN - 1] = (float)tag;

    // backtrace: out[row] = bp[row][tag] walking row = 8191..1
    for (int rb = S_LEN - 1; rb >= 1; rb -= 48) {
        const int jmax = (rb < 48) ? rb : 48;
        int bval[48];
#pragma unroll
        for (int j = 0; j < 48; j++)
            bval[j] = (j < jmax) ? (int)bp[(size_t)(rb - j) * TTAG + lane] : 0;
#pragma unroll
        for (int j = 0; j < 48; j++) {
            if (j < jmax) {
                tag = __shfl(bval[j], tag);
                if (lane == 0) out[rb - j] = (float)tag;
            }
        }
    }
}

// ---------------------------------------------------------------------------
extern "C" void kernel_launch(void* const* d_in, const int* in_sizes, int n_in,
                              void* d_out, int out_size, void* d_ws, size_t ws_size,
                              hipStream_t stream) {
    const float* sent = (const float*)d_in[0];
    const float* Wihf = (const float*)d_in[1];
    const float* Whhf = (const float*)d_in[2];
    const float* bihf = (const float*)d_in[3];
    const float* bhhf = (const float*)d_in[4];
    const float* Wihb = (const float*)d_in[5];
    const float* Whhb = (const float*)d_in[6];
    const float* bihb = (const float*)d_in[7];
    const float* bhhb = (const float*)d_in[8];
    const float* Wd = (const float*)d_in[9];
    const float* bd = (const float*)d_in[10];
    const float* trans = (const float*)d_in[11];
    float* out = (float*)d_out;

    float* ws = (float*)d_ws;
    float* xi_ring = ws;                                   // 8,388,608 f
    float* hall = ws + 8388608;                            // 16,777,216 f
    float* hrec = hall + 16777216;                         // 2*16*128*12 = 49,152 f
    float* cstate = hrec + 49152;                          // 2,048 f
    float* featsb = cstate + 2048;                         // 393,216 f
    float* wdT = featsb + 393216;                          // 98,304 f
    unsigned char* bp = (unsigned char*)(wdT + 98304);     // 393,216 B (+slack)

    wdt_kernel<<<dim3(384), dim3(256), 0, stream>>>(Wd, wdT);

    for (int c = 0; c < NCHUNK; c++) {
        gemm_xi<<<dim3(64, 16, 2), dim3(256), 0, stream>>>(
            sent, Wihf, Wihb, bihf, bhhf, bihb, bhhb, xi_ring, c);
        lstm_chunk<<<dim3(256), dim3(256), 0, stream>>>(
            xi_ring, hall, hrec, cstate, Whhf, Whhb, c);
    }

    feats_kernel<<<dim3(8192), dim3(256), 0, stream>>>(hall, wdT, bd, featsb);
    viterbi_kernel<<<dim3(1), dim3(64), 0, stream>>>(featsb, trans, bp, out);
}

// Round 5
// 26127.164 us; speedup vs baseline: 9.9668x; 1.1556x over previous
//
#include <hip/hip_runtime.h>

#define S_LEN 8192
#define HDIM 1024
#define TTAG 48
#define START_TAG 46
#define END_TAG 47
#define CHUNK 1024
#define NCHUNK 8
#define NSLOT 16   // h-record ring slots (producer/consumer skew <=1; ample)
#define VSEG 256   // viterbi segments
#define VLEN 32    // steps per segment (VSEG*VLEN == S_LEN)

typedef float f4 __attribute__((ext_vector_type(4)));

// Opaque 8x16B weight load (prevents compiler from sinking/remat the loads;
// forces the 128 weight floats per thread to stay VGPR-resident).
#define ASM_LD8(o0,o1,o2,o3,o4,o5,o6,o7,p)                                    \
  asm volatile("global_load_dwordx4 %0, %8, off\n\t"                          \
               "global_load_dwordx4 %1, %8, off offset:16\n\t"                \
               "global_load_dwordx4 %2, %8, off offset:32\n\t"                \
               "global_load_dwordx4 %3, %8, off offset:48\n\t"                \
               "global_load_dwordx4 %4, %8, off offset:64\n\t"                \
               "global_load_dwordx4 %5, %8, off offset:80\n\t"                \
               "global_load_dwordx4 %6, %8, off offset:96\n\t"                \
               "global_load_dwordx4 %7, %8, off offset:112\n\t"               \
               "s_waitcnt vmcnt(0)"                                           \
               : "=v"(o0),"=v"(o1),"=v"(o2),"=v"(o3),                         \
                 "=v"(o4),"=v"(o5),"=v"(o6),"=v"(o7)                          \
               : "v"(p) : "memory")

// LLC-direct (bypass L1/L2) 48-B record probe: three 16-B atoms, one wait.
#define ASM_POLL3(a0,a1,a2,p)                                                 \
  asm volatile("global_load_dwordx4 %0, %3, off sc0 sc1\n\t"                  \
               "global_load_dwordx4 %1, %3, off offset:16 sc0 sc1\n\t"        \
               "global_load_dwordx4 %2, %3, off offset:32 sc0 sc1\n\t"        \
               "s_waitcnt vmcnt(0)"                                           \
               : "=v"(a0),"=v"(a1),"=v"(a2) : "v"(p) : "memory")

// LLC write-through 16-B store (single transaction -> seq+data atomic).
#define ASM_ST_SC(p,v4)                                                       \
  asm volatile("global_store_dwordx4 %0, %1, off sc0 sc1"                     \
               :: "v"(p), "v"(v4) : "memory")

__device__ __forceinline__ void fma4(const f4 wv, const f4 hv, float& acc) {
    acc = fmaf(wv.x, hv.x, acc);
    acc = fmaf(wv.y, hv.y, acc);
    acc = fmaf(wv.z, hv.z, acc);
    acc = fmaf(wv.w, hv.w, acc);
}

// ---------------------------------------------------------------------------
// Transpose W_dense (48 x 2048) -> WdT (2048 x 48)
// ---------------------------------------------------------------------------
__global__ __launch_bounds__(256) void wdt_kernel(const float* __restrict__ Wd,
                                                  float* __restrict__ WdT) {
    int idx = blockIdx.x * 256 + threadIdx.x;
    if (idx < TTAG * 2048) {
        int tag = idx >> 11;
        int k = idx & 2047;
        WdT[(size_t)k * TTAG + tag] = Wd[idx];
    }
}

// ---------------------------------------------------------------------------
// xi GEMM (unchanged)
// ---------------------------------------------------------------------------
__global__ __launch_bounds__(256) void gemm_xi(
    const float* __restrict__ x,
    const float* __restrict__ Wf, const float* __restrict__ Wb,
    const float* __restrict__ bihf, const float* __restrict__ bhhf,
    const float* __restrict__ bihb, const float* __restrict__ bhhb,
    float* __restrict__ xi_ring, int chunk) {
    const int dir = blockIdx.z;
    const float* __restrict__ W = dir ? Wb : Wf;
    const float* __restrict__ bih = dir ? bihb : bihf;
    const float* __restrict__ bhh = dir ? bhhb : bhhf;

    const int mloc0 = blockIdx.y * 64;
    const int m0 = (dir == 0 ? chunk * CHUNK : S_LEN - (chunk + 1) * CHUNK) + mloc0;
    const int n0 = blockIdx.x * 64;

    __shared__ float As[16][68];
    __shared__ float Bs[16][68];

    const int tid = threadIdx.x;
    const int tx = tid & 15, ty = tid >> 4;
    const int lrow = tid >> 2, lk = (tid & 3) * 4;

    float acc[4][4];
#pragma unroll
    for (int a = 0; a < 4; a++)
#pragma unroll
        for (int b = 0; b < 4; b++) acc[a][b] = 0.f;

    const float* aptr = x + (size_t)(m0 + lrow) * HDIM + lk;
    const float* bptr = W + (size_t)(n0 + lrow) * HDIM + lk;

    for (int k0 = 0; k0 < HDIM; k0 += 16) {
        float4 av = *(const float4*)(aptr + k0);
        float4 bv = *(const float4*)(bptr + k0);
        __syncthreads();
        As[lk + 0][lrow] = av.x; As[lk + 1][lrow] = av.y;
        As[lk + 2][lrow] = av.z; As[lk + 3][lrow] = av.w;
        Bs[lk + 0][lrow] = bv.x; Bs[lk + 1][lrow] = bv.y;
        Bs[lk + 2][lrow] = bv.z; Bs[lk + 3][lrow] = bv.w;
        __syncthreads();
#pragma unroll
        for (int kk = 0; kk < 16; kk++) {
            float4 a4 = *(const float4*)&As[kk][ty * 4];
            float4 b4 = *(const float4*)&Bs[kk][tx * 4];
            float a[4] = {a4.x, a4.y, a4.z, a4.w};
            float b[4] = {b4.x, b4.y, b4.z, b4.w};
#pragma unroll
            for (int ii = 0; ii < 4; ii++)
#pragma unroll
                for (int jj = 0; jj < 4; jj++)
                    acc[ii][jj] = fmaf(a[ii], b[jj], acc[ii][jj]);
        }
    }

    const int n = n0 + tx * 4;
    const int gate = n >> 10;
    const int sl = (n & 1023) >> 3;
    const int e0 = n & 7;
    float4 bias;
    bias.x = bih[n + 0] + bhh[n + 0];
    bias.y = bih[n + 1] + bhh[n + 1];
    bias.z = bih[n + 2] + bhh[n + 2];
    bias.w = bih[n + 3] + bhh[n + 3];

#pragma unroll
    for (int ii = 0; ii < 4; ii++) {
        int mloc = mloc0 + ty * 4 + ii;
        int iloc = dir ? (CHUNK - 1 - mloc) : mloc;
        float4 v;
        v.x = acc[ii][0] + bias.x;
        v.y = acc[ii][1] + bias.y;
        v.z = acc[ii][2] + bias.z;
        v.w = acc[ii][3] + bias.w;
        *(float4*)(xi_ring + ((size_t)(dir * 128 + sl) * CHUNK + iloc) * 32 + gate * 8 + e0) = v;
    }
}

// ---------------------------------------------------------------------------
// Persistent LSTM chunk (unchanged from round 4)
// ---------------------------------------------------------------------------
__global__ __launch_bounds__(256, 1) void lstm_chunk(
    const float* __restrict__ xi_ring, float* __restrict__ hall,
    float* __restrict__ hrec, float* __restrict__ cstate,
    const float* __restrict__ Whhf, const float* __restrict__ Whhb, int chunk) {
    __shared__ float hsh[HDIM];
    __shared__ float psum[256];

    const int tid = threadIdx.x;
    const int bx = blockIdx.x;
    const int dir = bx >> 7;
    const int slice = bx & 127;
    const int row32 = tid & 31;
    const int kc = tid >> 5;
    const int gate = row32 >> 3;
    const int eloc = row32 & 7;

    const float* __restrict__ Whh = dir ? Whhb : Whhf;
    const int R = gate * HDIM + slice * 8 + eloc;
    const float* wsrc = Whh + (size_t)R * HDIM + kc * 128;

    f4 w00,w01,w02,w03,w04,w05,w06,w07,w08,w09,w10,w11,w12,w13,w14,w15;
    f4 w16,w17,w18,w19,w20,w21,w22,w23,w24,w25,w26,w27,w28,w29,w30,w31;
    ASM_LD8(w00,w01,w02,w03,w04,w05,w06,w07, wsrc);
    ASM_LD8(w08,w09,w10,w11,w12,w13,w14,w15, wsrc + 32);
    ASM_LD8(w16,w17,w18,w19,w20,w21,w22,w23, wsrc + 64);
    ASM_LD8(w24,w25,w26,w27,w28,w29,w30,w31, wsrc + 96);

    float creg = 0.f;
    if (chunk > 0 && tid < 8) creg = cstate[dir * HDIM + slice * 8 + tid];

    const size_t hbase = (size_t)dir * ((size_t)S_LEN * HDIM);
    f4* hsh4 = (f4*)hsh;

    for (int i = 0; i < CHUNK; i++) {
        const int t = chunk * CHUNK + i;

        float xi_v = 0.f;
        if (tid < 32) xi_v = xi_ring[((size_t)bx * CHUNK + (size_t)i) * 32 + tid];

        if (t == 0) {
            f4 z; z.x = 0.f; z.y = 0.f; z.z = 0.f; z.w = 0.f;
            hsh4[tid] = z;
        } else if (tid < 128) {
            const int j = (t - 1) & (NSLOT - 1);
            const float* rp = hrec + ((size_t)(dir * NSLOT + j) * 128 + tid) * 12;
            f4 a0, a1, a2;
            do {
                ASM_POLL3(a0, a1, a2, rp);
            } while (__float_as_int(a0.w) != t || __float_as_int(a1.w) != t ||
                     __float_as_int(a2.w) != t);
            f4 u, v;
            u.x = a0.x; u.y = a0.y; u.z = a0.z; u.w = a1.x;
            v.x = a1.y; v.y = a1.z; v.z = a2.x; v.w = a2.y;
            hsh4[2 * tid] = u;
            hsh4[2 * tid + 1] = v;
        }
        __syncthreads();

        float acc0 = 0.f, acc1 = 0.f, acc2 = 0.f, acc3 = 0.f;
        const f4* h4p = (const f4*)hsh + kc * 32;
        fma4(w00, h4p[0],  acc0); fma4(w01, h4p[1],  acc1);
        fma4(w02, h4p[2],  acc2); fma4(w03, h4p[3],  acc3);
        fma4(w04, h4p[4],  acc0); fma4(w05, h4p[5],  acc1);
        fma4(w06, h4p[6],  acc2); fma4(w07, h4p[7],  acc3);
        fma4(w08, h4p[8],  acc0); fma4(w09, h4p[9],  acc1);
        fma4(w10, h4p[10], acc2); fma4(w11, h4p[11], acc3);
        fma4(w12, h4p[12], acc0); fma4(w13, h4p[13], acc1);
        fma4(w14, h4p[14], acc2); fma4(w15, h4p[15], acc3);
        fma4(w16, h4p[16], acc0); fma4(w17, h4p[17], acc1);
        fma4(w18, h4p[18], acc2); fma4(w19, h4p[19], acc3);
        fma4(w20, h4p[20], acc0); fma4(w21, h4p[21], acc1);
        fma4(w22, h4p[22], acc2); fma4(w23, h4p[23], acc3);
        fma4(w24, h4p[24], acc0); fma4(w25, h4p[25], acc1);
        fma4(w26, h4p[26], acc2); fma4(w27, h4p[27], acc3);
        fma4(w28, h4p[28], acc0); fma4(w29, h4p[29], acc1);
        fma4(w30, h4p[30], acc2); fma4(w31, h4p[31], acc3);
        psum[kc * 32 + row32] = (acc0 + acc1) + (acc2 + acc3);
        __syncthreads();

        if (tid < 64) {
            const int l5 = tid & 31;
            float g = xi_v;
#pragma unroll
            for (int q = 0; q < 8; q++) g += psum[q * 32 + l5];
            const int e = tid & 7;
            float gI = __shfl(g, e);
            float gF = __shfl(g, 8 + e);
            float gG = __shfl(g, 16 + e);
            float gO = __shfl(g, 24 + e);
            float iv = 1.f / (1.f + expf(-gI));
            float fv = 1.f / (1.f + expf(-gF));
            float gv = tanhf(gG);
            float ov = 1.f / (1.f + expf(-gO));
            float cn = fv * creg + iv * gv;
            creg = cn;
            float hv = ov * tanhf(cn);

            float h0 = __shfl(hv, 0), h1 = __shfl(hv, 1), h2 = __shfl(hv, 2);
            float h3 = __shfl(hv, 3), h4 = __shfl(hv, 4), h5 = __shfl(hv, 5);
            float h6 = __shfl(hv, 6), h7 = __shfl(hv, 7);

            if (tid < 8)
                hall[hbase + (size_t)t * HDIM + slice * 8 + tid] = hv;
            if (tid < 3) {
                f4 av;
                av.x = (tid == 0) ? h0 : (tid == 1) ? h3 : h6;
                av.y = (tid == 0) ? h1 : (tid == 1) ? h4 : h7;
                av.z = (tid == 0) ? h2 : (tid == 1) ? h5 : h7;
                av.w = __int_as_float(t + 1);
                float* sp = hrec +
                    ((size_t)(dir * NSLOT + (t & (NSLOT - 1))) * 128 + slice) * 12 +
                    tid * 4;
                ASM_ST_SC(sp, av);
            }
        }
    }

    if (tid < 8) cstate[dir * HDIM + slice * 8 + tid] = creg;
}

// ---------------------------------------------------------------------------
// feats kernel (unchanged)
// ---------------------------------------------------------------------------
__global__ __launch_bounds__(256) void feats_kernel(
    const float* __restrict__ hall, const float* __restrict__ WdT,
    const float* __restrict__ bd, float* __restrict__ feats) {
    __shared__ float hsh[2048];
    __shared__ float red[TTAG * 256];
    __shared__ float red2[192];

    const int t = blockIdx.x;
    const int tid = threadIdx.x;

    ((float4*)hsh)[tid] = ((const float4*)(hall + (size_t)t * HDIM))[tid];
    ((float4*)hsh)[256 + tid] =
        ((const float4*)(hall + (size_t)S_LEN * HDIM + (size_t)(S_LEN - 1 - t) * HDIM))[tid];
    __syncthreads();

    float acc[TTAG];
#pragma unroll
    for (int j = 0; j < TTAG; j++) acc[j] = 0.f;

    const int kbase = tid * 8;
#pragma unroll
    for (int q = 0; q < 8; q++) {
        float hv = hsh[kbase + q];
        const float4* wr = (const float4*)(WdT + (size_t)(kbase + q) * TTAG);
#pragma unroll
        for (int p = 0; p < 12; p++) {
            float4 w = wr[p];
            acc[p * 4 + 0] = fmaf(hv, w.x, acc[p * 4 + 0]);
            acc[p * 4 + 1] = fmaf(hv, w.y, acc[p * 4 + 1]);
            acc[p * 4 + 2] = fmaf(hv, w.z, acc[p * 4 + 2]);
            acc[p * 4 + 3] = fmaf(hv, w.w, acc[p * 4 + 3]);
        }
    }
#pragma unroll
    for (int j = 0; j < TTAG; j++) red[j * 256 + tid] = acc[j];
    __syncthreads();

    if (tid < 192) {
        int tag = tid >> 2, p = tid & 3;
        float s = 0.f;
#pragma unroll
        for (int q = 0; q < 64; q++) s += red[tag * 256 + p * 64 + q];
        red2[tag * 4 + p] = s;
    }
    __syncthreads();

    if (tid < TTAG) {
        feats[(size_t)t * TTAG + tid] =
            red2[tid * 4] + red2[tid * 4 + 1] + red2[tid * 4 + 2] + red2[tid * 4 + 3] + bd[tid];
    }
}

// ---------------------------------------------------------------------------
// V1: per-segment max-plus matrix products.
// Pseg = M_{t0+31} (x) ... (x) M_{t0},  M_t[i][j] = trans[i][j] + feat[t][i].
// Layout: lane = row i (<48), wave (tid>>6) owns cols [wave*12, wave*12+12).
// LDS PL[b][j*48+k] holds P[k][j] (transposed) -> b128 broadcast reads.
// ---------------------------------------------------------------------------
__global__ __launch_bounds__(256) void vit_products(
    const float* __restrict__ feats, const float* __restrict__ trans,
    float* __restrict__ Pseg) {
    __shared__ float PL[2][TTAG * TTAG];
    __shared__ float fsh[VLEN * TTAG];

    const int tid = threadIdx.x;
    const int seg = blockIdx.x;
    const int lane = tid & 63;
    const int wave = tid >> 6;
    const int i = lane;
    const int ir = (i < TTAG) ? i : (TTAG - 1);

    const f4* ft = (const f4*)(feats + (size_t)seg * VLEN * TTAG);
    for (int q = tid; q < VLEN * TTAG / 4; q += 256)
        ((f4*)fsh)[q] = ft[q];

    float tr[TTAG];
#pragma unroll
    for (int k4 = 0; k4 < 12; k4++) {
        f4 v = ((const f4*)(trans + ir * TTAG))[k4];
        tr[k4 * 4 + 0] = v.x; tr[k4 * 4 + 1] = v.y;
        tr[k4 * 4 + 2] = v.z; tr[k4 * 4 + 3] = v.w;
    }
    __syncthreads();

    // init: P = M_first  (PL[0][j*48+i] = trans[i][j] + feat0[i])
    if (i < TTAG) {
        float f0 = fsh[i];
#pragma unroll
        for (int j12 = 0; j12 < 12; j12++) {
            int j = wave * 12 + j12;
            PL[0][j * TTAG + i] = trans[ir * TTAG + j] + f0;
        }
    }
    __syncthreads();

    int cur = 0;
    for (int step = 1; step < VLEN; step++) {
        const float* PLc = PL[cur];
        float* PLn = PL[cur ^ 1];
        float fstep = fsh[step * TTAG + ir];
#pragma unroll
        for (int j12 = 0; j12 < 12; j12++) {
            int j = wave * 12 + j12;
            const f4* pc = (const f4*)(PLc + j * TTAG);
            float m = -3.0e38f;
#pragma unroll
            for (int k4 = 0; k4 < 12; k4++) {
                f4 p = pc[k4];
                m = fmaxf(m, fmaxf(fmaxf(tr[k4 * 4 + 0] + p.x, tr[k4 * 4 + 1] + p.y),
                                   fmaxf(tr[k4 * 4 + 2] + p.z, tr[k4 * 4 + 3] + p.w)));
            }
            if (i < TTAG) PLn[j * TTAG + i] = fstep + m;
        }
        cur ^= 1;
        __syncthreads();
    }

    // store row-major: Pseg[seg][i][k] = PL[cur][k*48+i]; wave w does k-range
    if (i < TTAG) {
        float* outp = Pseg + (size_t)seg * (TTAG * TTAG) + i * TTAG;
#pragma unroll
        for (int k4 = 0; k4 < 3; k4++) {
            int k = wave * 12 + k4 * 4;
            f4 v;
            v.x = PL[cur][(k + 0) * TTAG + i];
            v.y = PL[cur][(k + 1) * TTAG + i];
            v.z = PL[cur][(k + 2) * TTAG + i];
            v.w = PL[cur][(k + 3) * TTAG + i];
            *(f4*)(outp + k) = v;
        }
    }
}

// ---------------------------------------------------------------------------
// V2: sequential fold of 256 segment matrices -> per-segment seed vectors.
// seeds[s] = fv at START of segment s; seeds[VSEG] = final fv.
// ---------------------------------------------------------------------------
__global__ __launch_bounds__(64) void vit_scan(
    const float* __restrict__ Pseg, float* __restrict__ seeds) {
    __shared__ float fvsh[64];
    const int lane = threadIdx.x;
    const int lr = (lane < TTAG) ? lane : (TTAG - 1);

    float fv = (lane == START_TAG) ? 0.f
             : (lane < TTAG) ? -10000.f : -3.0e38f;
    fvsh[lane] = fv;

    f4 pr[12], nx[12];
    const f4* rp0 = (const f4*)(Pseg + (size_t)lr * TTAG);
#pragma unroll
    for (int q = 0; q < 12; q++) pr[q] = rp0[q];

    for (int s = 0; s < VSEG; s++) {
        if (lane < TTAG) seeds[s * TTAG + lane] = fv;
        if (s < VSEG - 1) {
            const f4* np = (const f4*)(Pseg + (size_t)(s + 1) * (TTAG * TTAG) + lr * TTAG);
#pragma unroll
            for (int q = 0; q < 12; q++) nx[q] = np[q];
        }
        float fvv[TTAG];
#pragma unroll
        for (int jj = 0; jj < 12; jj++) {
            f4 v4 = *(const f4*)&fvsh[jj * 4];
            fvv[jj * 4 + 0] = v4.x; fvv[jj * 4 + 1] = v4.y;
            fvv[jj * 4 + 2] = v4.z; fvv[jj * 4 + 3] = v4.w;
        }
        float m = -3.0e38f;
#pragma unroll
        for (int q = 0; q < 12; q++) {
            f4 p = pr[q];
            m = fmaxf(m, fmaxf(fmaxf(p.x + fvv[q * 4 + 0], p.y + fvv[q * 4 + 1]),
                               fmaxf(p.z + fvv[q * 4 + 2], p.w + fvv[q * 4 + 3])));
        }
        fv = (lane < TTAG) ? m : -3.0e38f;
        fvsh[lane] = fv;   // single wave: LDS ops complete in issue order
#pragma unroll
        for (int q = 0; q < 12; q++) pr[q] = nx[q];
    }
    if (lane < TTAG) seeds[VSEG * TTAG + lane] = fv;
}

// ---------------------------------------------------------------------------
// V3: per-segment replay from seed, writing backpointers (exact reference
// semantics: first-index tie-break tournament, identical to round-4 code).
// ---------------------------------------------------------------------------
__global__ __launch_bounds__(64) void vit_replay(
    const float* __restrict__ feats, const float* __restrict__ trans,
    const float* __restrict__ seeds, unsigned char* __restrict__ bp) {
    __shared__ float fsh[VLEN * TTAG];
    __shared__ float fvsh[64];
    const int lane = threadIdx.x;
    const int seg = blockIdx.x;

    float tr[TTAG];
#pragma unroll
    for (int j = 0; j < TTAG; j++)
        tr[j] = (lane < TTAG) ? trans[lane * TTAG + j] : -3.0e38f;

    const f4* ft = (const f4*)(feats + (size_t)seg * VLEN * TTAG);
#pragma unroll
    for (int q = 0; q < 6; q++) ((f4*)fsh)[q * 64 + lane] = ft[q * 64 + lane];

    fvsh[lane] = (lane < TTAG) ? seeds[seg * TTAG + lane] : -3.0e38f;
    __syncthreads();

    for (int step = 0; step < VLEN; step++) {
        const int t = seg * VLEN + step;
        float feat = (lane < TTAG) ? fsh[step * TTAG + lane] : 0.f;

        float fvv[TTAG];
#pragma unroll
        for (int jj = 0; jj < 12; jj++) {
            f4 v4 = *(const f4*)&fvsh[jj * 4];
            fvv[jj * 4 + 0] = v4.x; fvv[jj * 4 + 1] = v4.y;
            fvv[jj * 4 + 2] = v4.z; fvv[jj * 4 + 3] = v4.w;
        }

        float v[64];
        int ix[64];
#pragma unroll
        for (int j = 0; j < TTAG; j++) { v[j] = fvv[j] + tr[j]; ix[j] = j; }
#pragma unroll
        for (int j = TTAG; j < 64; j++) { v[j] = -3.0e38f; ix[j] = j; }

#pragma unroll
        for (int len = 64; len > 1; len >>= 1) {
#pragma unroll
            for (int q = 0; q < (len >> 1); q++) {
                bool tb = v[2 * q + 1] > v[2 * q];  // tie -> keep lower index
                v[q] = tb ? v[2 * q + 1] : v[2 * q];
                ix[q] = tb ? ix[2 * q + 1] : ix[2 * q];
            }
        }

        if (lane < TTAG) bp[(size_t)t * TTAG + lane] = (unsigned char)ix[0];
        float nfv = (lane < TTAG) ? (v[0] + feat) : -3.0e38f;
        fvsh[lane] = nfv;  // single wave in-order LDS
    }
}

// ---------------------------------------------------------------------------
// V4: terminal argmax + blocked-shuffle backtrace (round-4 proven code).
// ---------------------------------------------------------------------------
__global__ __launch_bounds__(64) void vit_backtrace(
    const float* __restrict__ seeds, const float* __restrict__ trans,
    const unsigned char* __restrict__ bp, float* __restrict__ out) {
    __shared__ float fvsh[64];
    const int lane = threadIdx.x;

    float term = (lane < TTAG)
        ? seeds[VSEG * TTAG + lane] + trans[END_TAG * TTAG + lane]
        : -3.0e38f;
    fvsh[lane] = term;
    __syncthreads();

    int bl = 0;
    if (lane == 0) {
        float best = -3.4e38f;
        for (int i = 0; i < TTAG; i++) {
            if (fvsh[i] > best) { best = fvsh[i]; bl = i; }
        }
        out[0] = best;
    }
    int tag = __shfl(bl, 0);
    if (lane == 0) out[1 + S_LEN - 1] = (float)tag;

    for (int rb = S_LEN - 1; rb >= 1; rb -= 48) {
        const int jmax = (rb < 48) ? rb : 48;
        int bval[48];
#pragma unroll
        for (int j = 0; j < 48; j++)
            bval[j] = (j < jmax) ? (int)bp[(size_t)(rb - j) * TTAG + lane] : 0;
#pragma unroll
        for (int j = 0; j < 48; j++) {
            if (j < jmax) {
                tag = __shfl(bval[j], tag);
                if (lane == 0) out[rb - j] = (float)tag;
            }
        }
    }
}

// ---------------------------------------------------------------------------
extern "C" void kernel_launch(void* const* d_in, const int* in_sizes, int n_in,
                              void* d_out, int out_size, void* d_ws, size_t ws_size,
                              hipStream_t stream) {
    const float* sent = (const float*)d_in[0];
    const float* Wihf = (const float*)d_in[1];
    const float* Whhf = (const float*)d_in[2];
    const float* bihf = (const float*)d_in[3];
    const float* bhhf = (const float*)d_in[4];
    const float* Wihb = (const float*)d_in[5];
    const float* Whhb = (const float*)d_in[6];
    const float* bihb = (const float*)d_in[7];
    const float* bhhb = (const float*)d_in[8];
    const float* Wd = (const float*)d_in[9];
    const float* bd = (const float*)d_in[10];
    const float* trans = (const float*)d_in[11];
    float* out = (float*)d_out;

    float* ws = (float*)d_ws;
    float* xi_ring = ws;                                   // 8,388,608 f
    float* hall = ws + 8388608;                            // 16,777,216 f
    float* hrec = hall + 16777216;                         // 49,152 f
    float* cstate = hrec + 49152;                          // 2,048 f
    float* featsb = cstate + 2048;                         // 393,216 f
    float* wdT = featsb + 393216;                          // 98,304 f
    unsigned char* bp = (unsigned char*)(wdT + 98304);     // 393,216 B
    float* Pseg = wdT + 98304 + 98304;                     // 589,824 f
    float* seeds = Pseg + 589824;                          // 12,336 f

    wdt_kernel<<<dim3(384), dim3(256), 0, stream>>>(Wd, wdT);

    for (int c = 0; c < NCHUNK; c++) {
        gemm_xi<<<dim3(64, 16, 2), dim3(256), 0, stream>>>(
            sent, Wihf, Wihb, bihf, bhhf, bihb, bhhb, xi_ring, c);
        lstm_chunk<<<dim3(256), dim3(256), 0, stream>>>(
            xi_ring, hall, hrec, cstate, Whhf, Whhb, c);
    }

    feats_kernel<<<dim3(8192), dim3(256), 0, stream>>>(hall, wdT, bd, featsb);

    vit_products<<<dim3(VSEG), dim3(256), 0, stream>>>(featsb, trans, Pseg);
    vit_scan<<<dim3(1), dim3(64), 0, stream>>>(Pseg, seeds);
    vit_replay<<<dim3(VSEG), dim3(64), 0, stream>>>(featsb, trans, seeds, bp);
    vit_backtrace<<<dim3(1), dim3(64), 0, stream>>>(seeds, trans, bp, out);
}